// Round 16
// baseline (3311.301 us; speedup 1.0000x reference)
//
#include <hip/hip_runtime.h>
#include <stdint.h>

// CondDecoder: B=256, T=128, V=64, L=128, H=512, E=32, NL=3, IN0=161
// LAYER-PIPELINED mega-kernel, v2. 384 blocks = 3 layers x 16 rowgroups x 8
// colblocks, 256 threads (4 waves). Fused [Wih(pad512);Whh] (K=1024) streamed
// from L2 — XCD-SWIZZLED so all 16 rg of one (layer,cb) share an XCD:
// combo = bid%24 (24%8==0 -> XCD = combo%8), per-XCD distinct weights 1.2MB < 4MB L2.
// (R13's mega was correct but unswizzled: 9.2MB/XCD -> HBM thrash, FETCH 5.4GB.)
// No gi GEMMs. Protocol per R14: atomic publish + vmcnt drain + per-wave flags;
// PLAIN read-once pulls after flag detect. Single-buffered staging (38KB LDS)
// -> 2 blocks/CU co-residency guaranteed (384 <= 512 slots).
#define TT 128

typedef __attribute__((ext_vector_type(8))) short bf16x8;
typedef __attribute__((ext_vector_type(4))) float f32x4;
typedef __attribute__((ext_vector_type(4))) unsigned int u32x4;

__device__ __forceinline__ unsigned short f2bf(float f){
  unsigned int x = __builtin_bit_cast(unsigned int, f);
  x = x + 0x7fffu + ((x >> 16) & 1u);
  return (unsigned short)(x >> 16);
}
__device__ __forceinline__ float bf2f(unsigned short u){
  unsigned int x = ((unsigned int)u) << 16;
  return __builtin_bit_cast(float, x);
}

// ---- prep: fused [Wih(pad512);Whh] -> fragment-permuted bf16 per layer.
// dst i = (((wblk*3+g)*32+ks)*64+lane)*8+e ; wblk in [0,32) = gcol/16 ;
// k = ks*32+(lane>>4)*8+e in [0,1024): k<512 = x-part (pad kxr->512), else h-part.
__global__ __launch_bounds__(256) void kwf(const float* __restrict__ wih, int kxr,
    const float* __restrict__ whh, unsigned short* __restrict__ dst){
  size_t i = (size_t)blockIdx.x*256 + threadIdx.x;   // grid 6144 -> 1,572,864
  int e = (int)(i & 7), lane = (int)((i >> 3) & 63), ks = (int)((i >> 9) & 31);
  int rem = (int)(i >> 14);                          // wblk*3+g, < 96
  int g = rem % 3, wblk = rem / 3;
  int gr = g*512 + wblk*16 + (lane & 15);
  int k = ks*32 + ((lane >> 4) << 3) + e;
  float v;
  if (k < 512) v = (k < kxr) ? wih[(size_t)gr*kxr + k] : 0.f;
  else         v = whh[(size_t)gr*512 + (k - 512)];
  dst[i] = f2bf(v);
}

// ---- prep: fc_W transpose to [512][64] f32 + zero the 1536 flags
__global__ __launch_bounds__(256) void kfcw(const float* __restrict__ fcw,
    float* __restrict__ fcwt, int* __restrict__ flags){
  int i = blockIdx.x*256 + threadIdx.x;   // grid 128 -> 32768
  int k = i >> 6, v = i & 63;
  fcwt[i] = fcw[v*512 + k];
  if (blockIdx.x == 0){
    #pragma unroll
    for (int j = 0; j < 6; ++j) flags[threadIdx.x + j*256] = 0;
  }
}

// ---- prep: x0 [t*256+b][512] bf16 (latent | shifted-embed | enthalpy | zeros)
__global__ __launch_bounds__(256) void kx0(const float* __restrict__ latent,
    const float* __restrict__ enth, const int* __restrict__ inp,
    const float* __restrict__ emb, unsigned short* __restrict__ x0p){
  int m = blockIdx.x;                     // grid 32768
  int b = m & 255, t = m >> 8;
  for (int c = threadIdx.x; c < 512; c += 256){
    float v = 0.f;
    if (c < 128) v = latent[b*128 + c];
    else if (c < 160){
      int tok = (t == 0) ? 0 : inp[b*128 + t - 1];
      v = emb[tok*32 + (c - 128)];
    }
    else if (c == 160) v = enth[b];
    x0p[(size_t)m*512 + c] = f2bf(v);
  }
}

// ---- mega-kernel
__global__ __launch_bounds__(256, 2) void kmega(
    const unsigned short* __restrict__ Wp,     // [3][1,572,864] fused permuted
    const float* __restrict__ bih0, const float* __restrict__ bhh0,
    const float* __restrict__ bih1, const float* __restrict__ bhh1,
    const float* __restrict__ bih2, const float* __restrict__ bhh2,
    const unsigned short* __restrict__ x0p,
    unsigned short* __restrict__ hist0, unsigned short* __restrict__ hist1,
    unsigned short* __restrict__ hist2,
    float* __restrict__ x2f, int* __restrict__ flags){
  const int bid = blockIdx.x;                 // 384 blocks
  const int combo = bid % 24, rg = bid / 24;  // XCD = bid%8 = combo%8 (round-robin)
  const int l = combo >> 3, cb = combo & 7;
  const int b0 = rg*16;
  const int tid = threadIdx.x;
  const int w = tid >> 6, lane = tid & 63;
  const int c = lane & 15, lq = lane >> 4;
  const int gcol = cb*64 + w*16 + c;
  __shared__ __align__(16) unsigned short hsX[16*512];     // 16KB x-tile (single buf)
  __shared__ __align__(16) unsigned short hsH[16*512];     // 16KB own-h (single buf)
  __shared__ __align__(16) unsigned short hpub[4][256];    // 2KB publish shuffle
  __shared__ __align__(16) float hpf[4][256];              // 4KB f32 (layer 2)

  const float* bihp = (l == 0) ? bih0 : ((l == 1) ? bih1 : bih2);
  const float* bhhp = (l == 0) ? bhh0 : ((l == 1) ? bhh1 : bhh2);
  float bi[3], bh[3];
  #pragma unroll
  for (int g = 0; g < 3; ++g){ bi[g] = bihp[g*512 + gcol]; bh[g] = bhhp[g*512 + gcol]; }
  float h_old[4] = {0.f, 0.f, 0.f, 0.f};

  const unsigned short* xsrc = (l == 0) ? x0p : ((l == 1) ? hist0 : hist1);
  unsigned short* hdst = (l == 0) ? hist0 : ((l == 1) ? hist1 : hist2);
  const u32x4* xsrc16 = (const u32x4*)xsrc;
  const u32x4* hsrc16 = (const u32x4*)hdst;
  unsigned long long* hdst8 = (unsigned long long*)hdst;
  int* fown = flags + (l*16 + rg)*32;
  const int* fcrs = flags + ((l - 1)*16 + rg)*32;          // used when l>0
  // weight slice base: wblk = cb*4 + w
  const unsigned short* wb = Wp + (size_t)l*1572864 + (size_t)(cb*4 + w)*49152 + lane*8;
  const int prow = lane >> 2, qo = lane & 3;

  #pragma unroll 1
  for (int t = 0; t < TT; ++t){
    // A: polls (parallel: wave1 cross-layer, wave0 own-layer)
    if (l > 0 && w == 1){
      while (true){
        int f = __hip_atomic_load(fcrs + (lane & 31), __ATOMIC_RELAXED, __HIP_MEMORY_SCOPE_AGENT);
        if (__all(f >= t + 1)) break;
        __builtin_amdgcn_s_sleep(1);
      }
    }
    if (t > 0 && w == 0){
      while (true){
        int f = __hip_atomic_load(fown + (lane & 31), __ATOMIC_RELAXED, __HIP_MEMORY_SCOPE_AGENT);
        if (__all(f >= t)) break;
        __builtin_amdgcn_s_sleep(1);
      }
    }
    __syncthreads();   // polls done; also: every wave finished step t-1 MFMA (safe to overwrite LDS)
    // B: plain read-once pulls (16KB each) -> swizzled LDS
    {
      const u32x4* sx = xsrc16 + ((size_t)t*256 + b0)*64;
      u32x4 px[4];
      #pragma unroll
      for (int j = 0; j < 4; ++j) px[j] = sx[tid + j*256];
      u32x4 ph[4];
      if (t > 0){
        const u32x4* sh = hsrc16 + ((size_t)(t - 1)*256 + b0)*64;
        #pragma unroll
        for (int j = 0; j < 4; ++j) ph[j] = sh[tid + j*256];
      }
      #pragma unroll
      for (int j = 0; j < 4; ++j){
        int idx = tid + j*256;
        int row = idx >> 6, c16 = idx & 63;
        *(u32x4*)((char*)hsX + row*1024 + ((c16 ^ (row & 7)) << 4)) = px[j];
      }
      if (t > 0){
        #pragma unroll
        for (int j = 0; j < 4; ++j){
          int idx = tid + j*256;
          int row = idx >> 6, c16 = idx & 63;
          *(u32x4*)((char*)hsH + row*1024 + ((c16 ^ (row & 7)) << 4)) = ph[j];
        }
      }
    }
    __syncthreads();                               // staging complete
    // C: MFMA — weights streamed from (XCD-local) L2
    f32x4 ax[3] = {}, ah[3] = {};
    #pragma unroll
    for (int ks = 0; ks < 16; ++ks){
      bf16x8 af = *(const bf16x8*)((const char*)hsX + c*1024 + (((ks*4 + lq) ^ (c & 7)) << 4));
      ax[0] = __builtin_amdgcn_mfma_f32_16x16x32_bf16(af, *(const bf16x8*)(wb + 0*16384 + ks*512), ax[0], 0, 0, 0);
      ax[1] = __builtin_amdgcn_mfma_f32_16x16x32_bf16(af, *(const bf16x8*)(wb + 1*16384 + ks*512), ax[1], 0, 0, 0);
      ax[2] = __builtin_amdgcn_mfma_f32_16x16x32_bf16(af, *(const bf16x8*)(wb + 2*16384 + ks*512), ax[2], 0, 0, 0);
    }
    if (t > 0){
      #pragma unroll
      for (int ks = 0; ks < 16; ++ks){
        bf16x8 af = *(const bf16x8*)((const char*)hsH + c*1024 + (((ks*4 + lq) ^ (c & 7)) << 4));
        ah[0] = __builtin_amdgcn_mfma_f32_16x16x32_bf16(af, *(const bf16x8*)(wb + 0*16384 + (16 + ks)*512), ah[0], 0, 0, 0);
        ah[1] = __builtin_amdgcn_mfma_f32_16x16x32_bf16(af, *(const bf16x8*)(wb + 1*16384 + (16 + ks)*512), ah[1], 0, 0, 0);
        ah[2] = __builtin_amdgcn_mfma_f32_16x16x32_bf16(af, *(const bf16x8*)(wb + 2*16384 + (16 + ks)*512), ah[2], 0, 0, 0);
      }
    }
    // D: gates (fully in-lane; at t=0 ah=0 so h-part = bh, matching h0=0)
    unsigned short hv[4]; float hf[4];
    #pragma unroll
    for (int r = 0; r < 4; ++r){
      float rr = 1.f/(1.f + __expf(-(ax[0][r] + bi[0] + ah[0][r] + bh[0])));
      float zz = 1.f/(1.f + __expf(-(ax[1][r] + bi[1] + ah[1][r] + bh[1])));
      float np = ax[2][r] + bi[2] + rr*(ah[2][r] + bh[2]);
      float ee = __expf(2.f*np);
      float nn = 1.f - 2.f/(ee + 1.f);
      float hn = (1.f - zz)*nn + zz*h_old[r];
      h_old[r] = hn; hf[r] = hn; hv[r] = f2bf(hn);
    }
    // E: publish (wave-local shuffle -> 1x8B atomic/lane -> drain -> wave flag)
    #pragma unroll
    for (int r = 0; r < 4; ++r)
      hpub[w][(lq*4 + r)*16 + c] = hv[r];
    if (l == 2){
      #pragma unroll
      for (int r = 0; r < 4; ++r)
        hpf[w][(lq*4 + r)*16 + c] = hf[r];
    }
    __builtin_amdgcn_sched_barrier(0);
    unsigned long long pub = *(const unsigned long long*)&hpub[w][prow*16 + qo*4];
    __hip_atomic_store(hdst8 + ((size_t)t*256 + b0 + prow)*128 + cb*16 + w*4 + qo,
                       pub, __ATOMIC_RELAXED, __HIP_MEMORY_SCOPE_AGENT);
    asm volatile("s_waitcnt vmcnt(0)" ::: "memory");   // this wave's h at MALL
    if (lane == 0)
      __hip_atomic_store(fown + (cb*4 + w), t + 1, __ATOMIC_RELAXED, __HIP_MEMORY_SCOPE_AGENT);
    __builtin_amdgcn_sched_barrier(0);                 // x2f strictly after flag
    if (l == 2){
      f32x4 fv = *(const f32x4*)&hpf[w][prow*16 + qo*4];
      *(f32x4*)(x2f + ((size_t)t*256 + b0 + prow)*512 + cb*64 + w*16 + qo*4) = fv;
    }
  }
}

// ---- final FC in f32: logits[b][t][64] = x2f[(t,b)][512] @ fcwt + fc_b
__global__ __launch_bounds__(256) void kfc(const float* __restrict__ x,
    const float* __restrict__ wt, const float* __restrict__ fcb, float* __restrict__ out){
  __shared__ __align__(16) float xs[16*512];
  const int m0 = blockIdx.x*16;   // grid 2048
  for (int c = threadIdx.x; c < 2048; c += 256){
    int row = c >> 7, o = c & 127;
    *(f32x4*)&xs[row*512 + o*4] = *(const f32x4*)(x + (size_t)(m0+row)*512 + o*4);
  }
  __syncthreads();
  const int colv = threadIdx.x & 63, rq = threadIdx.x >> 6;
  float a0 = 0.f, a1 = 0.f, a2 = 0.f, a3 = 0.f;
  const float* x0p = xs + (rq*4 + 0)*512;
  const float* x1p = xs + (rq*4 + 1)*512;
  const float* x2p = xs + (rq*4 + 2)*512;
  const float* x3p = xs + (rq*4 + 3)*512;
  #pragma unroll 8
  for (int k = 0; k < 512; ++k){
    float w = wt[k*64 + colv];
    a0 += w * x0p[k]; a1 += w * x1p[k]; a2 += w * x2p[k]; a3 += w * x3p[k];
  }
  float bv = fcb[colv];
  float av[4] = {a0, a1, a2, a3};
  #pragma unroll
  for (int j = 0; j < 4; ++j){
    int m = m0 + rq*4 + j;
    int b = m & 255, t = m >> 8;               // (t,b) -> [b][t][64]
    out[((size_t)b*128 + t)*64 + colv] = av[j] + bv;
  }
}

extern "C" void kernel_launch(void* const* d_in, const int* in_sizes, int n_in,
                              void* d_out, int out_size, void* d_ws, size_t ws_size,
                              hipStream_t stream){
  const float* latent = (const float*)d_in[0];
  const float* enth   = (const float*)d_in[1];
  const int*   inp    = (const int*)d_in[2];
  const float* emb    = (const float*)d_in[3];
  const float* Wih0   = (const float*)d_in[4];
  const float* Whh0   = (const float*)d_in[5];
  const float* bih0   = (const float*)d_in[6];
  const float* bhh0   = (const float*)d_in[7];
  const float* Wih1   = (const float*)d_in[8];
  const float* Whh1   = (const float*)d_in[9];
  const float* bih1   = (const float*)d_in[10];
  const float* bhh1   = (const float*)d_in[11];
  const float* Wih2   = (const float*)d_in[12];
  const float* Whh2   = (const float*)d_in[13];
  const float* bih2   = (const float*)d_in[14];
  const float* bhh2   = (const float*)d_in[15];
  const float* fcW    = (const float*)d_in[16];
  const float* fcb    = (const float*)d_in[17];

  char* ws = (char*)d_ws;
  constexpr size_t SZH  = (size_t)32768*512*2;                  // 32MB
  constexpr size_t OFF_X0P  = 8192;                             // flags at 0 (6KB)
  constexpr size_t OFF_H0   = OFF_X0P + SZH;
  constexpr size_t OFF_H1   = OFF_H0  + SZH;
  constexpr size_t OFF_H2   = OFF_H1  + SZH;
  constexpr size_t OFF_X2F  = OFF_H2  + SZH;
  constexpr size_t OFF_WP   = OFF_X2F + (size_t)32768*512*4;    // 64MB
  constexpr size_t OFF_FCWT = OFF_WP  + (size_t)3*1572864*2;

  int* flags            = (int*)ws;
  unsigned short* x0p   = (unsigned short*)(ws + OFF_X0P);
  unsigned short* hist0 = (unsigned short*)(ws + OFF_H0);
  unsigned short* hist1 = (unsigned short*)(ws + OFF_H1);
  unsigned short* hist2 = (unsigned short*)(ws + OFF_H2);
  float* x2f            = (float*)(ws + OFF_X2F);
  unsigned short* wp    = (unsigned short*)(ws + OFF_WP);
  float* fcwt           = (float*)(ws + OFF_FCWT);

  kwf<<<6144, 256, 0, stream>>>(Wih0, 161, Whh0, wp);
  kwf<<<6144, 256, 0, stream>>>(Wih1, 512, Whh1, wp + (size_t)1572864);
  kwf<<<6144, 256, 0, stream>>>(Wih2, 512, Whh2, wp + (size_t)2*1572864);
  kfcw<<<128, 256, 0, stream>>>(fcW, fcwt, flags);
  kx0 <<<32768, 256, 0, stream>>>(latent, enth, inp, emb, x0p);
  kmega<<<384, 256, 0, stream>>>(wp, bih0, bhh0, bih1, bhh1, bih2, bhh2,
                                 x0p, hist0, hist1, hist2, x2f, flags);
  kfc <<<2048, 256, 0, stream>>>(x2f, fcwt, fcb, (float*)d_out);
}